// Round 2
// baseline (658.672 us; speedup 1.0000x reference)
//
#include <hip/hip_runtime.h>

// RPDC depthwise sparse-5x5 (pixel-difference) conv.
// x: (16,256,128,128) fp32, weight: (256,1,3,3) fp32, out same shape.
//
// out(h,w) = t0*(A[w-2]-B[w-1]) + t1*(A[w]-B[w]) + t2*(A[w+2]-B[w+1])
//          + t3*(C[w-2]-C[w-1]) + t4*(C[w+2]-C[w+1])
//          + t5*(E[w-2]-D[w-1]) + t6*(E[w]-D[w]) + t7*(E[w+2]-D[w+1])
// A..E = rows h-2..h+2 (zero pad), tj = weight flat [1+j].
//
// v3: one float4 load per row per lane; halo cols (w0-2,w0-1,w0+4,w0+5)
// pulled from neighbor lanes via ds_bpermute at insert time (they're already
// in registers) instead of extra float2 loads. 3-deep load pipeline
// (issue h+5, insert h+3, consume h+1..), 6-row register ring, full unroll.
// Wave = 2 adjacent chunks of one plane; bpermute edge lanes are exactly the
// zero-pad lanes (ml/mr = 0), so cross-strip leakage is masked away.

#define HH 128
#define WW 128
#define CHUNK 32               // rows per thread-strip
#define SPB 8                  // strips per 256-thread block

__device__ __forceinline__ float bperm(int addr, float v) {
    return __int_as_float(__builtin_amdgcn_ds_bpermute(addr, __float_as_int(v)));
}

__global__ __launch_bounds__(256, 5) void rpdc_kernel(
    const float* __restrict__ x, const float* __restrict__ wt,
    float* __restrict__ out, int C)
{
    const int tid   = threadIdx.x;
    const int l     = tid & 31;                      // col-group lane (4 cols)
    const int s     = blockIdx.x * SPB + (tid >> 5); // strip = (plane, chunk)
    const int plane = s >> 2;                        // n*C + c
    const int h0    = (s & 3) * CHUNK;
    const int c     = plane & (C - 1);               // C = 256 (pow2)

    const float* wp = wt + (size_t)c * 9;
    const float t0 = wp[1], t1 = wp[2], t2 = wp[3], t3 = wp[4];
    const float t4 = wp[5], t5 = wp[6], t6 = wp[7], t7 = wp[8];

    const int w0 = l * 4;                            // first owned column
    const float ml = (l == 0) ? 0.f : 1.f;           // zero-pad masks
    const float mr = (l == 31) ? 0.f : 1.f;

    // ds_bpermute byte addrs for lane +/- 1 (wave-wrap; edges masked by ml/mr)
    const int lane = tid & 63;
    const int upA  = ((lane - 1) & 63) * 4;
    const int dnA  = ((lane + 1) & 63) * 4;

    const float* xb = x + (size_t)plane * (HH * WW) + (size_t)h0 * WW + w0;
    float* ob = out + (size_t)plane * (HH * WW) + (size_t)h0 * WW + w0;

    // ring[(rr+2)%6] holds relative row rr, 8 cols w0-2..w0+5
    float ring[6][8];
    float4 s0, s1;                                   // staged rows h+3, h+4

    auto issue = [&](int rr, float4& v) {
        const int r = h0 + rr;                       // absolute row
        if ((unsigned)r < (unsigned)HH) {
            v = *(const float4*)(xb + rr * WW);
        } else {
            v = make_float4(0.f, 0.f, 0.f, 0.f);     // zero pad / drained
        }
    };
    auto insert = [&](float (&row)[8], const float4& v) {
        row[0] = bperm(upA, v.z) * ml;               // col w0-2 (lane l-1 .z)
        row[1] = bperm(upA, v.w) * ml;               // col w0-1
        row[2] = v.x; row[3] = v.y; row[4] = v.z; row[5] = v.w;
        row[6] = bperm(dnA, v.x) * mr;               // col w0+4 (lane l+1 .x)
        row[7] = bperm(dnA, v.y) * mr;               // col w0+5
    };

    // prologue: rows rr = -2..2 -> slots 0..4; stage rr = 3, 4
#pragma unroll
    for (int k = 0; k < 5; ++k) {
        float4 v;
        issue(k - 2, v);
        insert(ring[k], v);
    }
    issue(3, s0);
    issue(4, s1);

#pragma unroll
    for (int h = 0; h < CHUNK; ++h) {
        // stage-1: issue row rr = h+5 (needed rows go up to CHUNK+1)
        float4 nv;
        issue((h <= CHUNK - 4) ? (h + 5) : HH, nv);

        // stage-2: shuffle-extend + insert row rr = h+3 (loaded 2 iters ago)
        insert(ring[(h + 5) % 6], s0);
        s0 = s1; s1 = nv;                            // renamed by full unroll

        const float (&A)[8]  = ring[h % 6];          // rr h-2
        const float (&B)[8]  = ring[(h + 1) % 6];    // rr h-1
        const float (&Cc)[8] = ring[(h + 2) % 6];    // rr h
        const float (&D)[8]  = ring[(h + 3) % 6];    // rr h+1
        const float (&E)[8]  = ring[(h + 4) % 6];    // rr h+2

        float o[4];
#pragma unroll
        for (int j = 0; j < 4; ++j) {                // arr[k] = col w0-2+k
            float r = t0 * (A[j]     - B[j + 1]);
            r      += t1 * (A[j + 2] - B[j + 2]);
            r      += t2 * (A[j + 4] - B[j + 3]);
            r      += t3 * (Cc[j]     - Cc[j + 1]);
            r      += t4 * (Cc[j + 4] - Cc[j + 3]);
            r      += t5 * (E[j]     - D[j + 1]);
            r      += t6 * (E[j + 2] - D[j + 2]);
            r      += t7 * (E[j + 4] - D[j + 3]);
            o[j] = r;
        }
        *(float4*)(ob + h * WW) = make_float4(o[0], o[1], o[2], o[3]);
    }
}

extern "C" void kernel_launch(void* const* d_in, const int* in_sizes, int n_in,
                              void* d_out, int out_size, void* d_ws, size_t ws_size,
                              hipStream_t stream) {
    const float* x = (const float*)d_in[0];
    const float* wt = (const float*)d_in[1];
    float* out = (float*)d_out;

    const int C = in_sizes[1] / 9;                 // 256
    const int planes = in_sizes[0] / (HH * WW);    // N*C = 4096

    // strips = planes * (HH/CHUNK); 8 strips (2 planes) per 256-thread block
    dim3 grid(planes * (HH / CHUNK) / SPB);        // 2048
    dim3 block(256);
    rpdc_kernel<<<grid, block, 0, stream>>>(x, wt, out, C);
}

// Round 3
// 436.782 us; speedup vs baseline: 1.5080x; 1.5080x over previous
//
#include <hip/hip_runtime.h>

// RPDC depthwise sparse-5x5 (pixel-difference) conv.
// x: (16,256,128,128) fp32, weight: (256,1,3,3) fp32, out same shape.
//
// out(h,w) = t0*(A[w-2]-B[w-1]) + t1*(A[w]-B[w]) + t2*(A[w+2]-B[w+1])
//          + t3*(C[w-2]-C[w-1]) + t4*(C[w+2]-C[w+1])
//          + t5*(E[w-2]-D[w-1]) + t6*(E[w]-D[w]) + t7*(E[w+2]-D[w+1])
// A..E = rows h-2..h+2 (zero pad), tj = weight flat [1+j].
//
// v4 = v3 with __launch_bounds__(256,4). v3's (256,5) capped VGPRs at 102;
// the kernel needs ~110, so the 6x8 ring spilled to scratch (evidence:
// VGPR_Count=48, WRITE_SIZE 268->486 MB, VALUBusy 6%). Cap 128 fits it.
//
// Structure: one float4 load per row per lane; halo cols (w0-2,w0-1,w0+4,
// w0+5) pulled from neighbor lanes via ds_bpermute at insert time. 3-deep
// load pipeline (issue h+5, insert h+3, consume h+1..), 6-row ring, full
// unroll. Wave = 2 adjacent strips; bpermute edge lanes are exactly the
// zero-pad lanes (ml/mr = 0), so cross-strip leakage is masked away.

#define HH 128
#define WW 128
#define CHUNK 32               // rows per thread-strip
#define SPB 8                  // strips per 256-thread block

__device__ __forceinline__ float bperm(int addr, float v) {
    return __int_as_float(__builtin_amdgcn_ds_bpermute(addr, __float_as_int(v)));
}

__global__ __launch_bounds__(256, 4) void rpdc_kernel(
    const float* __restrict__ x, const float* __restrict__ wt,
    float* __restrict__ out, int C)
{
    const int tid   = threadIdx.x;
    const int l     = tid & 31;                      // col-group lane (4 cols)
    const int s     = blockIdx.x * SPB + (tid >> 5); // strip = (plane, chunk)
    const int plane = s >> 2;                        // n*C + c
    const int h0    = (s & 3) * CHUNK;
    const int c     = plane & (C - 1);               // C = 256 (pow2)

    const float* wp = wt + (size_t)c * 9;
    const float t0 = wp[1], t1 = wp[2], t2 = wp[3], t3 = wp[4];
    const float t4 = wp[5], t5 = wp[6], t6 = wp[7], t7 = wp[8];

    const int w0 = l * 4;                            // first owned column
    const float ml = (l == 0) ? 0.f : 1.f;           // zero-pad masks
    const float mr = (l == 31) ? 0.f : 1.f;

    // ds_bpermute byte addrs for lane +/- 1 (wave-wrap; edges masked by ml/mr)
    const int lane = tid & 63;
    const int upA  = ((lane - 1) & 63) * 4;
    const int dnA  = ((lane + 1) & 63) * 4;

    const float* xb = x + (size_t)plane * (HH * WW) + (size_t)h0 * WW + w0;
    float* ob = out + (size_t)plane * (HH * WW) + (size_t)h0 * WW + w0;

    // ring[(rr+2)%6] holds relative row rr, 8 cols w0-2..w0+5
    float ring[6][8];
    float4 s0, s1;                                   // staged rows h+3, h+4

    auto issue = [&](int rr, float4& v) {
        const int r = h0 + rr;                       // absolute row
        if ((unsigned)r < (unsigned)HH) {
            v = *(const float4*)(xb + rr * WW);
        } else {
            v = make_float4(0.f, 0.f, 0.f, 0.f);     // zero pad / drained
        }
    };
    auto insert = [&](float (&row)[8], const float4& v) {
        row[0] = bperm(upA, v.z) * ml;               // col w0-2 (lane l-1 .z)
        row[1] = bperm(upA, v.w) * ml;               // col w0-1
        row[2] = v.x; row[3] = v.y; row[4] = v.z; row[5] = v.w;
        row[6] = bperm(dnA, v.x) * mr;               // col w0+4 (lane l+1 .x)
        row[7] = bperm(dnA, v.y) * mr;               // col w0+5
    };

    // prologue: rows rr = -2..2 -> slots 0..4; stage rr = 3, 4
#pragma unroll
    for (int k = 0; k < 5; ++k) {
        float4 v;
        issue(k - 2, v);
        insert(ring[k], v);
    }
    issue(3, s0);
    issue(4, s1);

#pragma unroll
    for (int h = 0; h < CHUNK; ++h) {
        // stage-1: issue row rr = h+5 (needed rows go up to CHUNK+1)
        float4 nv;
        issue((h <= CHUNK - 4) ? (h + 5) : HH, nv);

        // stage-2: shuffle-extend + insert row rr = h+3 (loaded 2 iters ago)
        insert(ring[(h + 5) % 6], s0);
        s0 = s1; s1 = nv;                            // renamed by full unroll

        const float (&A)[8]  = ring[h % 6];          // rr h-2
        const float (&B)[8]  = ring[(h + 1) % 6];    // rr h-1
        const float (&Cc)[8] = ring[(h + 2) % 6];    // rr h
        const float (&D)[8]  = ring[(h + 3) % 6];    // rr h+1
        const float (&E)[8]  = ring[(h + 4) % 6];    // rr h+2

        float o[4];
#pragma unroll
        for (int j = 0; j < 4; ++j) {                // arr[k] = col w0-2+k
            float r = t0 * (A[j]     - B[j + 1]);
            r      += t1 * (A[j + 2] - B[j + 2]);
            r      += t2 * (A[j + 4] - B[j + 3]);
            r      += t3 * (Cc[j]     - Cc[j + 1]);
            r      += t4 * (Cc[j + 4] - Cc[j + 3]);
            r      += t5 * (E[j]     - D[j + 1]);
            r      += t6 * (E[j + 2] - D[j + 2]);
            r      += t7 * (E[j + 4] - D[j + 3]);
            o[j] = r;
        }
        *(float4*)(ob + h * WW) = make_float4(o[0], o[1], o[2], o[3]);
    }
}

extern "C" void kernel_launch(void* const* d_in, const int* in_sizes, int n_in,
                              void* d_out, int out_size, void* d_ws, size_t ws_size,
                              hipStream_t stream) {
    const float* x = (const float*)d_in[0];
    const float* wt = (const float*)d_in[1];
    float* out = (float*)d_out;

    const int C = in_sizes[1] / 9;                 // 256
    const int planes = in_sizes[0] / (HH * WW);    // N*C = 4096

    // strips = planes * (HH/CHUNK); 8 strips (2 planes) per 256-thread block
    dim3 grid(planes * (HH / CHUNK) / SPB);        // 2048
    dim3 block(256);
    rpdc_kernel<<<grid, block, 0, stream>>>(x, wt, out, C);
}